// Round 16
// baseline (332.858 us; speedup 1.0000x reference)
//
#include <hip/hip_runtime.h>
#include <hip/hip_bf16.h>
#include <stdint.h>

typedef float  f32x4  __attribute__((ext_vector_type(4)));
typedef __bf16 bf16x8 __attribute__((ext_vector_type(8)));
typedef unsigned int u32;
typedef u32 u32v2 __attribute__((ext_vector_type(2)));

#define GRID   2048
#define TROWS  16               // rows per tile
#define ITERS  8                // GRID * ITERS * TROWS = 262144 rows
#define TILEB  (TROWS * 1024)   // 16 KB f32 tile, LINEAR (gload_lds req)
#define NBUF   3                // 48 KB LDS ring -> 3 blocks/CU
#define WSB    65536            // code table: 8192 frags * 8 B

// exp_proj onto {sign(w) * 0.25 * 2^k, k=0..4}; boundaries at 0.25*2^(k+0.5)
__device__ __forceinline__ float qlog(float v) {
    float a = fabsf(v);
    int k = (a >= 0.35355339059327373f)
          + (a >= 0.70710678118654746f)
          + (a >= 1.41421356237309515f)
          + (a >= 2.82842712474619029f);
    float q = 0.25f * (float)(1 << k);
    return (v == 0.0f) ? 0.0f : copysignf(q, v);
}

// 1-byte code: sign<<7 | (bf16_exponent - 64). Grid exps 125..129 -> 61..65.
__device__ __forceinline__ u32 enc1(float q) {
    u32 b16 = __float_as_uint(q) >> 16;
    return b16 ? (((b16 >> 8) & 0x80u) | (((b16 >> 7) & 0xFFu) - 64u)) : 0u;
}
// decode 2 codes in u16 lanes: bf16 = (code + (code&0x80) + 64) << 7
__device__ __forceinline__ u32 dec2(u32 d) {
    u32 t = d & 0x00800080u;
    return (d + t + 0x00400040u) << 7;
}
__device__ __forceinline__ bf16x8 dec_frag(u32 c0, u32 c1) {
#if __has_builtin(__builtin_amdgcn_perm)
    u32 d0 = __builtin_amdgcn_perm(0u, c0, 0x0C010C00u);
    u32 d1 = __builtin_amdgcn_perm(0u, c0, 0x0C030C02u);
    u32 d2 = __builtin_amdgcn_perm(0u, c1, 0x0C010C00u);
    u32 d3 = __builtin_amdgcn_perm(0u, c1, 0x0C030C02u);
#else
    u32 d0 = (c0 & 0xFFu) | ((c0 & 0xFF00u) << 8);
    u32 d1 = ((c0 >> 16) & 0xFFu) | ((c0 & 0xFF000000u) >> 8);
    u32 d2 = (c1 & 0xFFu) | ((c1 & 0xFF00u) << 8);
    u32 d3 = ((c1 >> 16) & 0xFFu) | ((c1 & 0xFF000000u) >> 8);
#endif
    union { u32 u[4]; bf16x8 v; } u_;
    u_.u[0] = dec2(d0); u_.u[1] = dec2(d1);
    u_.u[2] = dec2(d2); u_.u[3] = dec2(d3);
    return u_.v;
}

// async global->LDS, 16 B/lane; LDS dest wave-uniform base + lane*16
__device__ __forceinline__ void gload16(const float* g, char* l) {
#if __has_builtin(__builtin_amdgcn_global_load_lds)
    __builtin_amdgcn_global_load_lds(
        (const __attribute__((address_space(1))) u32*)g,
        (__attribute__((address_space(3))) u32*)l, 16, 0, 0);
#else
    const int lane = threadIdx.x & 63;
    *(f32x4*)(l + lane * 16) = *(const f32x4*)(g + lane * 4);
#endif
}

// kernel 1: quantize weight -> 1-byte-code frag table.
// frag f = (ntile*8 + kt)*64 + lane ; codes of w_q[n][k0..k0+7],
// n = ntile*16 + (lane&15), k0 = kt*32 + (lane>>4)*8.
__global__ __launch_bounds__(256) void lqw_quant(
    const float* __restrict__ w, u32v2* __restrict__ wsq)
{
    const int gid  = blockIdx.x * 256 + threadIdx.x;
    const int lane = gid & 63;
    const int kt   = (gid >> 6) & 7;
    const int ntv  = gid >> 9;
    const float* src = w + (size_t)(ntv * 16 + (lane & 15)) * 256
                         + kt * 32 + (lane >> 4) * 8;
    u32v2 c = (u32v2){0, 0};
    #pragma unroll
    for (int e = 0; e < 4; ++e) c[0] |= enc1(qlog(src[e]))     << (8 * e);
    #pragma unroll
    for (int e = 0; e < 4; ++e) c[1] |= enc1(qlog(src[4 + e])) << (8 * e);
    wsq[gid] = c;
    __threadfence();
}

template<bool USE_WS>
__global__ __launch_bounds__(512, 6) void lqw_gemm(
    const float* __restrict__ in,    // [262144][256]
    const float* __restrict__ w,     // [256][256]
    const float* __restrict__ bias,  // [256]
    const u32v2* __restrict__ wsq,
    float* __restrict__ out)         // [262144][256]
{
    __shared__ __align__(16) char smem[NBUF * TILEB];   // 49152 B
    const int tid  = threadIdx.x;
    const int lane = tid & 63;
    const int wv   = tid >> 6;       // wave 0..7 owns 32 output cols
    const int nbase = wv * 32;
    const int lrow = lane & 15;
    const int kgrp = lane >> 4;
    const int s    = lrow & 7;       // per-row XOR swizzle key (16B units)
    const int o0 = ((kgrp * 2)     ^ s) * 16;
    const int o1 = ((kgrp * 2 + 1) ^ s) * 16;

    // ---- quantized B codes (8 B per frag -> 32 VGPRs) ----
    u32v2 bc[2][8];
    if (USE_WS) {
        #pragma unroll
        for (int nt = 0; nt < 2; ++nt)
            #pragma unroll
            for (int kt = 0; kt < 8; ++kt)
                bc[nt][kt] = wsq[(size_t)((wv * 2 + nt) * 8 + kt) * 64 + lane];
    } else {
        #pragma unroll
        for (int nt = 0; nt < 2; ++nt) {
            const float* wrow = w + (size_t)(nbase + nt * 16 + lrow) * 256;
            #pragma unroll
            for (int kt = 0; kt < 8; ++kt) {
                u32v2 c = (u32v2){0, 0};
                #pragma unroll
                for (int e = 0; e < 4; ++e)
                    c[0] |= enc1(qlog(wrow[kt * 32 + kgrp * 8 + e])) << (8 * e);
                #pragma unroll
                for (int e = 0; e < 4; ++e)
                    c[1] |= enc1(qlog(wrow[kt * 32 + kgrp * 8 + 4 + e])) << (8 * e);
                bc[nt][kt] = c;
            }
        }
    }
    // bias for swapped-D layout: lane holds n = nbase + nt*16 + kgrp*4 + rg
    f32x4 bv[2];
    #pragma unroll
    for (int nt = 0; nt < 2; ++nt)
        bv[nt] = *(const f32x4*)(bias + nbase + nt * 16 + kgrp * 4);

    const int mt0 = blockIdx.x * ITERS;

    // stage 16-row tile mt -> ring buffer: 2 rows per wave, 1 KB per gload.
    // global source column-unit XOR-swizzled by row&7; LDS stays linear.
    #define STAGE(bi, mt) do {                                              \
        char* _d = smem + (bi) * TILEB;                                     \
        _Pragma("unroll")                                                   \
        for (int j = 0; j < 2; ++j) {                                       \
            const int r = wv * 2 + j;                                       \
            const float* _s = in + ((size_t)(mt) * TROWS + r) * 256         \
                                 + ((lane ^ (r & 7)) << 2);                 \
            gload16(_s, _d + r * 1024);                                     \
        }                                                                   \
    } while (0)

    #define COMPUTE(bi, mt) do {                                                            \
        const char* row0 = smem + (bi) * TILEB + (size_t)lrow * 1024;                       \
        f32x4 acc[2];                                                                       \
        acc[0] = bv[0]; acc[1] = bv[1];                                                     \
        _Pragma("unroll")                                                                   \
        for (int kt = 0; kt < 8; ++kt) {                                                    \
            f32x4 lo = *(const f32x4*)(row0 + kt * 128 + o0);                               \
            f32x4 hi = *(const f32x4*)(row0 + kt * 128 + o1);                               \
            bf16x8 a0;                                                                      \
            _Pragma("unroll")                                                               \
            for (int e = 0; e < 4; ++e) { a0[e] = (__bf16)lo[e]; a0[4 + e] = (__bf16)hi[e]; } \
            bf16x8 b0 = dec_frag(bc[0][kt][0], bc[0][kt][1]);                               \
            bf16x8 b1 = dec_frag(bc[1][kt][0], bc[1][kt][1]);                               \
            acc[0] = __builtin_amdgcn_mfma_f32_16x16x32_bf16(b0, a0, acc[0], 0, 0, 0);      \
            acc[1] = __builtin_amdgcn_mfma_f32_16x16x32_bf16(b1, a0, acc[1], 0, 0, 0);      \
        }                                                                                   \
        float* orow = out + (size_t)((mt) * TROWS + lrow) * 256 + nbase + kgrp * 4;         \
        *(f32x4*)(orow)      = acc[0];                                                      \
        *(f32x4*)(orow + 16) = acc[1];                                                      \
    } while (0)

    // ---- prologue: stage tiles 0,1; full drain; publish ----
    STAGE(0, mt0);
    STAGE(1, mt0 + 1);
    asm volatile("s_waitcnt vmcnt(0)" ::: "memory");
    __builtin_amdgcn_s_barrier();

    // fully unrolled: ring indices & fence immediates are compile-time.
    #pragma unroll
    for (int t = 0; t < ITERS; ++t) {
        if (t + 2 < ITERS) STAGE((t + 2) % NBUF, mt0 + t + 2);  // 2 gloads
        __builtin_amdgcn_sched_barrier(0);   // pin gloads before COMPUTE's stores
        COMPUTE(t % NBUF, mt0 + t);          // 16 ds_read + 16 MFMA + 2 stores
        if (t + 2 < ITERS) {
            // queue (old->new): g(t+1)2 s(t-1)2 g(t+2)2 s(t)2 -> vmcnt(6)
            // forces g(t+1) (next iter's buffer) without draining the rest.
            asm volatile("s_waitcnt vmcnt(6) lgkmcnt(0)" ::: "memory");
        } else {
            // tail (no stage issued): newest 4 = s(t)2 s(t-1)2 -> vmcnt(4)
            // forces the last staged tile's gloads.
            asm volatile("s_waitcnt vmcnt(4) lgkmcnt(0)" ::: "memory");
        }
        __builtin_amdgcn_sched_barrier(0);
        __builtin_amdgcn_s_barrier();
    }
}

extern "C" void kernel_launch(void* const* d_in, const int* in_sizes, int n_in,
                              void* d_out, int out_size, void* d_ws, size_t ws_size,
                              hipStream_t stream) {
    const float* in_p   = (const float*)d_in[0];
    const float* w_p    = (const float*)d_in[1];
    const float* bias_p = (const float*)d_in[2];
    float* out_p        = (float*)d_out;
    if (ws_size >= WSB) {
        u32v2* wsq = (u32v2*)d_ws;
        lqw_quant<<<32, 256, 0, stream>>>(w_p, wsq);
        lqw_gemm<true><<<GRID, 512, 0, stream>>>(in_p, w_p, bias_p, wsq, out_p);
    } else {
        lqw_gemm<false><<<GRID, 512, 0, stream>>>(in_p, w_p, bias_p, nullptr, out_p);
    }
}

// Round 17
// 114.611 us; speedup vs baseline: 2.9042x; 2.9042x over previous
//
#include <hip/hip_runtime.h>
#include <hip/hip_bf16.h>
#include <stdint.h>

typedef float  f32x4  __attribute__((ext_vector_type(4)));
typedef __bf16 bf16x8 __attribute__((ext_vector_type(8)));
typedef unsigned int u32;
typedef u32 u32v2 __attribute__((ext_vector_type(2)));

#define GRID   2048
#define TROWS  16               // rows per tile
#define ITERS  8                // GRID * ITERS * TROWS = 262144 rows
#define TILEB  (TROWS * 1024)   // 16 KB f32 tile, LINEAR (gload_lds req)
#define NBUF   3                // 48 KB LDS ring -> 3 blocks/CU (144 <= 160 KB)
#define WSB    65536            // code table: 8192 frags * 8 B

// exp_proj onto {sign(w) * 0.25 * 2^k, k=0..4}; boundaries at 0.25*2^(k+0.5)
__device__ __forceinline__ float qlog(float v) {
    float a = fabsf(v);
    int k = (a >= 0.35355339059327373f)
          + (a >= 0.70710678118654746f)
          + (a >= 1.41421356237309515f)
          + (a >= 2.82842712474619029f);
    float q = 0.25f * (float)(1 << k);
    return (v == 0.0f) ? 0.0f : copysignf(q, v);
}

// 1-byte code: sign<<7 | (bf16_exponent - 64). Grid exps 125..129 -> 61..65.
__device__ __forceinline__ u32 enc1(float q) {
    u32 b16 = __float_as_uint(q) >> 16;
    return b16 ? (((b16 >> 8) & 0x80u) | (((b16 >> 7) & 0xFFu) - 64u)) : 0u;
}
// decode 2 codes in u16 lanes: bf16 = (code + (code&0x80) + 64) << 7
__device__ __forceinline__ u32 dec2(u32 d) {
    u32 t = d & 0x00800080u;
    return (d + t + 0x00400040u) << 7;
}
__device__ __forceinline__ bf16x8 dec_frag(u32 c0, u32 c1) {
#if __has_builtin(__builtin_amdgcn_perm)
    u32 d0 = __builtin_amdgcn_perm(0u, c0, 0x0C010C00u);
    u32 d1 = __builtin_amdgcn_perm(0u, c0, 0x0C030C02u);
    u32 d2 = __builtin_amdgcn_perm(0u, c1, 0x0C010C00u);
    u32 d3 = __builtin_amdgcn_perm(0u, c1, 0x0C030C02u);
#else
    u32 d0 = (c0 & 0xFFu) | ((c0 & 0xFF00u) << 8);
    u32 d1 = ((c0 >> 16) & 0xFFu) | ((c0 & 0xFF000000u) >> 8);
    u32 d2 = (c1 & 0xFFu) | ((c1 & 0xFF00u) << 8);
    u32 d3 = ((c1 >> 16) & 0xFFu) | ((c1 & 0xFF000000u) >> 8);
#endif
    union { u32 u[4]; bf16x8 v; } u_;
    u_.u[0] = dec2(d0); u_.u[1] = dec2(d1);
    u_.u[2] = dec2(d2); u_.u[3] = dec2(d3);
    return u_.v;
}

// async global->LDS, 16 B/lane; LDS dest wave-uniform base + lane*16
__device__ __forceinline__ void gload16(const float* g, char* l) {
#if __has_builtin(__builtin_amdgcn_global_load_lds)
    __builtin_amdgcn_global_load_lds(
        (const __attribute__((address_space(1))) u32*)g,
        (__attribute__((address_space(3))) u32*)l, 16, 0, 0);
#else
    const int lane = threadIdx.x & 63;
    *(f32x4*)(l + lane * 16) = *(const f32x4*)(g + lane * 4);
#endif
}

// kernel 1: quantize weight -> 1-byte-code frag table.
// frag f = (ntile*8 + kt)*64 + lane ; codes of w_q[n][k0..k0+7],
// n = ntile*16 + (lane&15), k0 = kt*32 + (lane>>4)*8.
__global__ __launch_bounds__(256) void lqw_quant(
    const float* __restrict__ w, u32v2* __restrict__ wsq)
{
    const int gid  = blockIdx.x * 256 + threadIdx.x;
    const int lane = gid & 63;
    const int kt   = (gid >> 6) & 7;
    const int ntv  = gid >> 9;
    const float* src = w + (size_t)(ntv * 16 + (lane & 15)) * 256
                         + kt * 32 + (lane >> 4) * 8;
    u32v2 c = (u32v2){0, 0};
    #pragma unroll
    for (int e = 0; e < 4; ++e) c[0] |= enc1(qlog(src[e]))     << (8 * e);
    #pragma unroll
    for (int e = 0; e < 4; ++e) c[1] |= enc1(qlog(src[4 + e])) << (8 * e);
    wsq[gid] = c;
    __threadfence();
}

template<bool USE_WS>
__global__ __launch_bounds__(512, 4) void lqw_gemm(
    const float* __restrict__ in,    // [262144][256]
    const float* __restrict__ w,     // [256][256]
    const float* __restrict__ bias,  // [256]
    const u32v2* __restrict__ wsq,
    float* __restrict__ out)         // [262144][256]
{
    __shared__ __align__(16) char smem[NBUF * TILEB];   // 49152 B
    const int tid  = threadIdx.x;
    const int lane = tid & 63;
    const int wv   = tid >> 6;       // wave 0..7 owns 32 output cols
    const int nbase = wv * 32;
    const int lrow = lane & 15;
    const int kgrp = lane >> 4;
    const int s    = lrow & 7;       // per-row XOR swizzle key (16B units)
    const int o0 = ((kgrp * 2)     ^ s) * 16;
    const int o1 = ((kgrp * 2 + 1) ^ s) * 16;

    // ---- quantized B codes (8 B per frag -> 32 VGPRs) ----
    u32v2 bc[2][8];
    if (USE_WS) {
        #pragma unroll
        for (int nt = 0; nt < 2; ++nt)
            #pragma unroll
            for (int kt = 0; kt < 8; ++kt)
                bc[nt][kt] = wsq[(size_t)((wv * 2 + nt) * 8 + kt) * 64 + lane];
    } else {
        #pragma unroll
        for (int nt = 0; nt < 2; ++nt) {
            const float* wrow = w + (size_t)(nbase + nt * 16 + lrow) * 256;
            #pragma unroll
            for (int kt = 0; kt < 8; ++kt) {
                u32v2 c = (u32v2){0, 0};
                #pragma unroll
                for (int e = 0; e < 4; ++e)
                    c[0] |= enc1(qlog(wrow[kt * 32 + kgrp * 8 + e])) << (8 * e);
                #pragma unroll
                for (int e = 0; e < 4; ++e)
                    c[1] |= enc1(qlog(wrow[kt * 32 + kgrp * 8 + 4 + e])) << (8 * e);
                bc[nt][kt] = c;
            }
        }
    }
    // bias for swapped-D layout: lane holds n = nbase + nt*16 + kgrp*4 + rg
    f32x4 bv[2];
    #pragma unroll
    for (int nt = 0; nt < 2; ++nt)
        bv[nt] = *(const f32x4*)(bias + nbase + nt * 16 + kgrp * 4);

    const int mt0 = blockIdx.x * ITERS;

    // stage 16-row tile mt -> ring buffer: 2 rows per wave, 1 KB per gload.
    // global source column-unit XOR-swizzled by row&7; LDS stays linear.
    #define STAGE(bi, mt) do {                                              \
        char* _d = smem + (bi) * TILEB;                                     \
        _Pragma("unroll")                                                   \
        for (int j = 0; j < 2; ++j) {                                       \
            const int r = wv * 2 + j;                                       \
            const float* _s = in + ((size_t)(mt) * TROWS + r) * 256         \
                                 + ((lane ^ (r & 7)) << 2);                 \
            gload16(_s, _d + r * 1024);                                     \
        }                                                                   \
    } while (0)

    #define COMPUTE(bi, mt) do {                                                            \
        const char* row0 = smem + (bi) * TILEB + (size_t)lrow * 1024;                       \
        f32x4 acc[2];                                                                       \
        acc[0] = bv[0]; acc[1] = bv[1];                                                     \
        _Pragma("unroll")                                                                   \
        for (int kt = 0; kt < 8; ++kt) {                                                    \
            f32x4 lo = *(const f32x4*)(row0 + kt * 128 + o0);                               \
            f32x4 hi = *(const f32x4*)(row0 + kt * 128 + o1);                               \
            bf16x8 a0;                                                                      \
            _Pragma("unroll")                                                               \
            for (int e = 0; e < 4; ++e) { a0[e] = (__bf16)lo[e]; a0[4 + e] = (__bf16)hi[e]; } \
            bf16x8 b0 = dec_frag(bc[0][kt][0], bc[0][kt][1]);                               \
            bf16x8 b1 = dec_frag(bc[1][kt][0], bc[1][kt][1]);                               \
            acc[0] = __builtin_amdgcn_mfma_f32_16x16x32_bf16(b0, a0, acc[0], 0, 0, 0);      \
            acc[1] = __builtin_amdgcn_mfma_f32_16x16x32_bf16(b1, a0, acc[1], 0, 0, 0);      \
        }                                                                                   \
        float* orow = out + (size_t)((mt) * TROWS + lrow) * 256 + nbase + kgrp * 4;         \
        *(f32x4*)(orow)      = acc[0];                                                      \
        *(f32x4*)(orow + 16) = acc[1];                                                      \
    } while (0)

    // ---- prologue: stage tiles 0,1; force g0 (g1 may stay in flight) ----
    STAGE(0, mt0);
    STAGE(1, mt0 + 1);
    asm volatile("s_waitcnt vmcnt(2)" ::: "memory");
    __builtin_amdgcn_s_barrier();

    // main loop: stage-ahead 2 into a 3-buffer ring. Per iter issue order:
    // g(t+2)x2 then s(t)x2. End-of-iter queue (old->new):
    // [g(t+1)2, s(t-1)2, g(t+2)2, s(t)2] -> vmcnt(6) forces g(t+1) exactly.
    #pragma unroll
    for (int t = 0; t < ITERS - 2; ++t) {
        STAGE((t + 2) % NBUF, mt0 + t + 2);
        __builtin_amdgcn_sched_barrier(0);   // pin gloads before COMPUTE's stores
        COMPUTE(t % NBUF, mt0 + t);
        asm volatile("s_waitcnt vmcnt(6) lgkmcnt(0)" ::: "memory");
        __builtin_amdgcn_sched_barrier(0);
        __builtin_amdgcn_s_barrier();
    }
    // t = ITERS-2: no stage. Queue after stores (old->new):
    // [s(IT-4)2, g(IT-1)2, s(IT-3)2, s(IT-2)2] -> vmcnt(4) forces g(IT-1).
    COMPUTE((ITERS - 2) % NBUF, mt0 + ITERS - 2);
    asm volatile("s_waitcnt vmcnt(4) lgkmcnt(0)" ::: "memory");
    __builtin_amdgcn_sched_barrier(0);
    __builtin_amdgcn_s_barrier();
    // t = ITERS-1: final tile, no fence needed after.
    COMPUTE((ITERS - 1) % NBUF, mt0 + ITERS - 1);
}

extern "C" void kernel_launch(void* const* d_in, const int* in_sizes, int n_in,
                              void* d_out, int out_size, void* d_ws, size_t ws_size,
                              hipStream_t stream) {
    const float* in_p   = (const float*)d_in[0];
    const float* w_p    = (const float*)d_in[1];
    const float* bias_p = (const float*)d_in[2];
    float* out_p        = (float*)d_out;
    if (ws_size >= WSB) {
        u32v2* wsq = (u32v2*)d_ws;
        lqw_quant<<<32, 256, 0, stream>>>(w_p, wsq);
        lqw_gemm<true><<<GRID, 512, 0, stream>>>(in_p, w_p, bias_p, wsq, out_p);
    } else {
        lqw_gemm<false><<<GRID, 512, 0, stream>>>(in_p, w_p, bias_p, nullptr, out_p);
    }
}